// Round 1
// 100.103 us; speedup vs baseline: 1.0657x; 1.0657x over previous
//
#include <hip/hip_runtime.h>

#define N 8192
#define D 256
#define NB 64                        // number of 128-row blocks
#define NTILES (NB * (NB + 1) / 2)   // 2080 upper-triangle tiles

typedef float f32x4 __attribute__((ext_vector_type(4)));
typedef long long i64;

// async global->LDS, 16 bytes/lane; LDS dest is wave-uniform base + lane*16
__device__ __forceinline__ void gload16(const void* g, void* lds) {
    __builtin_amdgcn_global_load_lds(
        (const __attribute__((address_space(1))) void*)g,
        (__attribute__((address_space(3))) void*)lds, 16, 0, 0);
}

// u32 key: [31:13] = float bits of val (val>=0, 10-bit mantissa kept),
// [12:0] = 0x1FFF - idx. u32 max == (max val, tie -> min idx) up to
// truncation; finalize recomputes distances exactly in fp32.

// ---------------------------------------------------------------- kernel 0
// prep: fp8 (OCP e4m3) convert + row norms + zero keys + zero out
__global__ __launch_bounds__(256) void prep_kernel(const float* __restrict__ q,
                                                   unsigned char* __restrict__ q8,
                                                   float* __restrict__ sq,
                                                   unsigned* __restrict__ pos_key,
                                                   unsigned* __restrict__ neg_key,
                                                   float* __restrict__ out) {
    const int row = blockIdx.x * 4 + (threadIdx.x >> 6);
    const int lane = threadIdx.x & 63;
    if (threadIdx.x < 8) {
        const int r0 = blockIdx.x * 4 + (threadIdx.x >> 1);
        if (threadIdx.x & 1) neg_key[r0] = 0u; else pos_key[r0] = 0u;
    }
    if (blockIdx.x == 0 && threadIdx.x == 0) out[0] = 0.0f;
    const float4 v = ((const float4*)(q + row * D))[lane];
    int r = 0;
    r = __builtin_amdgcn_cvt_pk_fp8_f32(v.x, v.y, r, false);  // bytes 0,1
    r = __builtin_amdgcn_cvt_pk_fp8_f32(v.z, v.w, r, true);   // bytes 2,3
    ((int*)(q8 + (size_t)row * D))[lane] = r;
    float s = v.x * v.x + v.y * v.y + v.z * v.z + v.w * v.w;
    #pragma unroll
    for (int off = 32; off; off >>= 1) s += __shfl_down(s, off, 64);
    if (lane == 0) sq[row] = s;
}

// ---------------------------------------------------------------- kernel 1
// Symmetric fp8 MFMA miner: 256 thd = 2x2 waves, 128x128 tile, wave 64x64
// via 4x4 frags of 16x16x32_fp8_fp8.  NEW (this round): software-pipelined
// K-loop with counted vmcnt (T4) — chunk c+1's global_load_lds stay in
// flight across the barrier (never vmcnt(0) mid-loop), double-buffered
// 2x16KB panels aliased over the merge LDS.  Eliminates the 4x per-block
// full vmcnt(0) latency drains of the previous 2-barrier structure.
// setprio(1) wraps the MFMA cluster (T5: waves now role-desynced).
// Diag tiles stage B redundantly so every thread issues exactly 4 loads
// per chunk (wave-uniform vmcnt immediates).
__global__ __launch_bounds__(256, 3) void mine_kernel(
    const unsigned char* __restrict__ q8, const int* __restrict__ tgt,
    const float* __restrict__ sqv,
    unsigned* __restrict__ pos_key, unsigned* __restrict__ neg_key)
{
    __shared__ __align__(16) unsigned Msh[2 * 128 * 33];  // merge; front 32KB = 2x staging bufs
    __shared__ float sqI[128], sqJ[128];
    __shared__ int   tgI[128], tgJ[128];
    char* const smem = (char*)Msh;   // buf0: A[0,8K) B[8K,16K); buf1: +16K

    // triangular tile map: blockIdx.x -> (bi, bj), bi <= bj
    int tt = blockIdx.x, bi = 0;
    while (tt >= NB - bi) { tt -= NB - bi; ++bi; }
    const int bj = bi + tt;
    const int i0 = bi * 128, j0 = bj * 128;
    const bool diag = (bi == bj);

    const int tid = threadIdx.x;
    const int w = tid >> 6, lane = tid & 63;
    const int quad = lane >> 4, lc = lane & 15;
    const int wy = w >> 1, wx = w & 1;

    // stage chunk cc into buffer bb (4 gload16 per thread, fixed order)
#define STAGE(cc, bb) do {                                                   \
        const int _dk = (cc) * 64;                                           \
        { const int _s = tid; const int _r = _s >> 2, _bo = (_s & 3) * 16;   \
          const int _lb = (bb) * 16384 + (w * 64) * 16;                      \
          gload16(q8 + (size_t)(i0 + _r) * D + _dk + _bo, smem + _lb);       \
          gload16(q8 + (size_t)(j0 + _r) * D + _dk + _bo, smem + 8192 + _lb); } \
        { const int _s = 256 + tid; const int _r = _s >> 2, _bo = (_s & 3) * 16; \
          const int _lb = (bb) * 16384 + (256 + w * 64) * 16;                \
          gload16(q8 + (size_t)(i0 + _r) * D + _dk + _bo, smem + _lb);       \
          gload16(q8 + (size_t)(j0 + _r) * D + _dk + _bo, smem + 8192 + _lb); } \
    } while (0)

    if (tid < 128) { sqI[tid] = sqv[i0 + tid]; tgI[tid] = tgt[i0 + tid]; }
    else { const int c = tid - 128; sqJ[c] = sqv[j0 + c]; tgJ[c] = tgt[j0 + c]; }

    // prologue prefetch: chunk 0 in flight while we init accumulators
    STAGE(0, 0);
    // sq/tg ds_writes visible to all waves; chunk-0 vmcnt stays outstanding
    asm volatile("s_waitcnt lgkmcnt(0)\n\ts_barrier" ::: "memory");

    // acc init: -(si + sqj)/2  =>  after MFMA chain, acc = -dist/2
    float sqjn[4];
    #pragma unroll
    for (int nt = 0; nt < 4; ++nt) sqjn[nt] = sqJ[wx * 64 + nt * 16 + lc];
    f32x4 acc[4][4];
    #pragma unroll
    for (int mt = 0; mt < 4; ++mt) {
        const f32x4 si4 = *(const f32x4*)&sqI[wy * 64 + mt * 16 + quad * 4];
        #pragma unroll
        for (int nt = 0; nt < 4; ++nt)
            #pragma unroll
            for (int r = 0; r < 4; ++r)
                acc[mt][nt][r] = -0.5f * (si4[r] + sqjn[nt]);
    }

    // K-loop: 4 chunks of K=64, 1-deep pipelined, counted vmcnt
    #pragma unroll
    for (int c = 0; c < 4; ++c) {
        if (c < 3) {
            STAGE(c + 1, (c + 1) & 1);
            // wait for chunk c's 4 loads only; c+1's 4 stay in flight
            asm volatile("s_waitcnt vmcnt(4)\n\ts_barrier" ::: "memory");
        } else {
            asm volatile("s_waitcnt vmcnt(0)\n\ts_barrier" ::: "memory");
        }
        const char* AP = smem + (c & 1) * 16384;
        const char* BP = AP + 8192;
        union { int4 v; i64 d[2]; } fb[4], fa;
        #pragma unroll
        for (int t = 0; t < 4; ++t)
            fb[t].v = *(const int4*)(BP + (wx * 64 + t * 16 + lc) * 64 + quad * 16);
        __builtin_amdgcn_s_setprio(1);
        #pragma unroll
        for (int mt = 0; mt < 4; ++mt) {
            fa.v = *(const int4*)(AP + (wy * 64 + mt * 16 + lc) * 64 + quad * 16);
            #pragma unroll
            for (int nt = 0; nt < 4; ++nt) {
                acc[mt][nt] = __builtin_amdgcn_mfma_f32_16x16x32_fp8_fp8(
                    fa.d[0], fb[nt].d[0], acc[mt][nt], 0, 0, 0);
                acc[mt][nt] = __builtin_amdgcn_mfma_f32_16x16x32_fp8_fp8(
                    fa.d[1], fb[nt].d[1], acc[mt][nt], 0, 0, 0);
            }
        }
        __builtin_amdgcn_s_setprio(0);
        // frag reads of buf[c&1] done before anyone stages chunk c+2 into it
        asm volatile("s_waitcnt lgkmcnt(0)\n\ts_barrier" ::: "memory");
    }
#undef STAGE
    // last trailing barrier above also makes staging LDS reusable as merge

    unsigned* const mpos = Msh;
    unsigned* const mneg = Msh + 128 * 33;

    // ---- epilogue: u32 keys, LDS-merge I-side, shuffle-merge J-side
    int tj[4]; unsigned jc[4], jpk[4], jnk[4];
    #pragma unroll
    for (int nt = 0; nt < 4; ++nt) {
        const int cl = wx * 64 + nt * 16 + lc;
        tj[nt] = tgJ[cl];
        jc[nt] = 0x1FFFu - (unsigned)(j0 + cl);   // I-side idx field (col)
        jpk[nt] = 0u; jnk[nt] = 0u;
    }

    #pragma unroll
    for (int mt = 0; mt < 4; ++mt) {
        const int rbase = wy * 64 + mt * 16 + quad * 4;
        const int4 ti4 = *(const int4*)&tgI[rbase];
        #pragma unroll
        for (int r = 0; r < 4; ++r) {
            const int sr = rbase + r;
            const unsigned rk = 0x1FFFu - (unsigned)(i0 + sr);  // J idx field
            const int ti = ((const int*)&ti4)[r];
            unsigned bpk = 0u, bnk = 0u;
            #pragma unroll
            for (int nt = 0; nt < 4; ++nt) {
                const int cl = wx * 64 + nt * 16 + lc;
                const float dist = fmaxf(-2.0f * acc[mt][nt][r], 0.0f);
                const unsigned db = __float_as_uint(dist) & 0xFFFFE000u;
                const bool same = (ti == tj[nt]);
                const bool dia = diag && (sr == cl);
                const unsigned pb_ = dia ? 0u : (same ? db : 0u);
                const unsigned nb_ = dia ? 0u : (same ? 0u : db);
                bpk = max(bpk, dia ? 0u : (pb_ | jc[nt]));
                bnk = max(bnk, dia ? 0u : (nb_ | jc[nt]));
                jpk[nt] = max(jpk[nt], dia ? 0u : (pb_ | rk));
                jnk[nt] = max(jnk[nt], dia ? 0u : (nb_ | rk));
            }
            mpos[sr * 33 + wx * 16 + lc] = bpk;
            mneg[sr * 33 + wx * 16 + lc] = bnk;
        }
    }
    __syncthreads();

    // I-side owner merge: tid<128 -> pos row tid; tid>=128 -> neg row tid-128
    {
        const int sr = tid & 127;
        const unsigned* m = (tid < 128) ? &mpos[sr * 33] : &mneg[sr * 33];
        unsigned best = 0u;
        #pragma unroll
        for (int k = 0; k < 32; ++k) best = max(best, m[k]);
        unsigned* gk = (tid < 128) ? pos_key : neg_key;
        atomicMax(&gk[i0 + sr], best);
    }

    // J-side: merge 4 quads within wave, then atomic (both wy waves emit)
    if (!diag) {
        #pragma unroll
        for (int nt = 0; nt < 4; ++nt) {
            unsigned pk = jpk[nt], nk = jnk[nt];
            #pragma unroll
            for (int off = 16; off < 64; off <<= 1) {
                pk = max(pk, (unsigned)__shfl_xor((int)pk, off, 64));
                nk = max(nk, (unsigned)__shfl_xor((int)nk, off, 64));
            }
            if (quad == 0) {
                const int gcol = j0 + wx * 64 + nt * 16 + lc;
                atomicMax(&pos_key[gcol], pk);
                atomicMax(&neg_key[gcol], nk);
            }
        }
    }
}

// ---------------------------------------------------------------- kernel 2
// Fused finalize + mean.  NEW: 512 blocks x 4 rows/wave (was 64 x 32):
// 2048 waves = 8 waves/CU so the random qp/qn row gathers are latency-
// hidden by TLP instead of serialized 32-deep on 1 wave/CU.
__global__ __launch_bounds__(256) void final_kernel(
    const float* __restrict__ q, const unsigned* __restrict__ pos_key,
    const unsigned* __restrict__ neg_key, float* __restrict__ out)
{
    __shared__ float red[4];
    const int wv = threadIdx.x >> 6, lane = threadIdx.x & 63;
    float wsum = 0.0f;
    #pragma unroll
    for (int rr = 0; rr < 4; ++rr) {
        const int row = (blockIdx.x * 4 + wv) * 4 + rr;
        const int bpi = 0x1FFF - (int)(pos_key[row] & 0x1FFFu);
        const int bni = 0x1FFF - (int)(neg_key[row] & 0x1FFFu);
        const float4 qi = ((const float4*)(q + row * D))[lane];
        const float4 qp = ((const float4*)(q + (size_t)bpi * D))[lane];
        const float4 qn = ((const float4*)(q + (size_t)bni * D))[lane];
        float dx, dp = 0.0f, dn = 0.0f;
        dx = qi.x - qp.x; dp += dx * dx;
        dx = qi.y - qp.y; dp += dx * dx;
        dx = qi.z - qp.z; dp += dx * dx;
        dx = qi.w - qp.w; dp += dx * dx;
        dx = qi.x - qn.x; dn += dx * dx;
        dx = qi.y - qn.y; dn += dx * dx;
        dx = qi.z - qn.z; dn += dx * dx;
        dx = qi.w - qn.w; dn += dx * dx;
        #pragma unroll
        for (int off = 32; off; off >>= 1) {
            dp += __shfl_down(dp, off, 64);
            dn += __shfl_down(dn, off, 64);
        }
        if (lane == 0) wsum += fmaxf(0.0f, (1.0f - dp) + dn);
    }
    if (lane == 0) red[wv] = wsum;
    __syncthreads();
    if (threadIdx.x == 0)
        atomicAdd(out, (red[0] + red[1] + red[2] + red[3]) * (1.0f / N));
}

// ----------------------------------------------------------------
extern "C" void kernel_launch(void* const* d_in, const int* in_sizes, int n_in,
                              void* d_out, int out_size, void* d_ws, size_t ws_size,
                              hipStream_t stream) {
    const float* q = (const float*)d_in[0];
    const int* tgt = (const int*)d_in[1];
    float* out = (float*)d_out;

    // ws layout (~2.2 MB)
    unsigned* pos_key = (unsigned*)d_ws;              // N
    unsigned* neg_key = pos_key + N;                  // N
    unsigned char* q8 = (unsigned char*)(neg_key + N);// N*D bytes
    float* sqv = (float*)(q8 + (size_t)N * D);        // N

    prep_kernel<<<dim3(N / 4), dim3(256), 0, stream>>>(q, q8, sqv, pos_key, neg_key, out);
    mine_kernel<<<dim3(NTILES), dim3(256), 0, stream>>>(q8, tgt, sqv, pos_key, neg_key);
    final_kernel<<<dim3(512), dim3(256), 0, stream>>>(q, pos_key, neg_key, out);
}

// Round 2
// 97.942 us; speedup vs baseline: 1.0892x; 1.0221x over previous
//
#include <hip/hip_runtime.h>

#define N 8192
#define D 256
#define NB 64                        // number of 128-row blocks
#define NTILES (NB * (NB + 1) / 2)   // 2080 upper-triangle tiles

typedef float f32x4 __attribute__((ext_vector_type(4)));
typedef long long i64;

// async global->LDS, 16 bytes/lane; LDS dest is wave-uniform base + lane*16
__device__ __forceinline__ void gload16(const void* g, void* lds) {
    __builtin_amdgcn_global_load_lds(
        (const __attribute__((address_space(1))) void*)g,
        (__attribute__((address_space(3))) void*)lds, 16, 0, 0);
}

// u32 key: [31:13] = float bits of val (val>=0, 10-bit mantissa kept),
// [12:0] = 0x1FFF - idx. u32 max == (max val, tie -> min idx) up to
// truncation; finalize recomputes distances exactly in fp32.

// ---------------------------------------------------------------- kernel 0
// prep: fp8 (OCP e4m3) convert + row norms + zero keys + zero out
__global__ __launch_bounds__(256) void prep_kernel(const float* __restrict__ q,
                                                   unsigned char* __restrict__ q8,
                                                   float* __restrict__ sq,
                                                   unsigned* __restrict__ pos_key,
                                                   unsigned* __restrict__ neg_key,
                                                   float* __restrict__ out) {
    const int row = blockIdx.x * 4 + (threadIdx.x >> 6);
    const int lane = threadIdx.x & 63;
    if (threadIdx.x < 8) {
        const int r0 = blockIdx.x * 4 + (threadIdx.x >> 1);
        if (threadIdx.x & 1) neg_key[r0] = 0u; else pos_key[r0] = 0u;
    }
    if (blockIdx.x == 0 && threadIdx.x == 0) out[0] = 0.0f;
    const float4 v = ((const float4*)(q + row * D))[lane];
    int r = 0;
    r = __builtin_amdgcn_cvt_pk_fp8_f32(v.x, v.y, r, false);  // bytes 0,1
    r = __builtin_amdgcn_cvt_pk_fp8_f32(v.z, v.w, r, true);   // bytes 2,3
    ((int*)(q8 + (size_t)row * D))[lane] = r;
    float s = v.x * v.x + v.y * v.y + v.z * v.z + v.w * v.w;
    #pragma unroll
    for (int off = 32; off; off >>= 1) s += __shfl_down(s, off, 64);
    if (lane == 0) sq[row] = s;
}

// ---------------------------------------------------------------- kernel 1
// Symmetric fp8 MFMA miner: 256 thd = 2x2 waves, 128x128 tile, wave 64x64
// via 4x4 frags of 16x16x32_fp8_fp8.  Pipelined K-loop (counted vmcnt,
// 2x16KB double-buffered panels aliased over merge LDS).
// NEW (this round): epilogue specialized on the block-uniform `diag` flag.
//  - non-diag (2016/2080 blocks): masked "jc / rk" candidates are hoisted
//    into the key inits (bpk=bnk=jc[0], jpk=jnk=0x1FFF-i0 — these dominate
//    every masked candidate and contribute identically to the global max),
//    so the per-element update is kI/kJ build + 4x {max,cndmask} on `same`.
//    ~13 VALU ops/elem vs ~18 before.
//  - diag: drops the (never-consumed) J-side jpk/jnk updates.
__global__ __launch_bounds__(256, 3) void mine_kernel(
    const unsigned char* __restrict__ q8, const int* __restrict__ tgt,
    const float* __restrict__ sqv,
    unsigned* __restrict__ pos_key, unsigned* __restrict__ neg_key)
{
    __shared__ __align__(16) unsigned Msh[2 * 128 * 33];  // merge; front 32KB = 2x staging bufs
    __shared__ float sqI[128], sqJ[128];
    __shared__ int   tgI[128], tgJ[128];
    char* const smem = (char*)Msh;   // buf0: A[0,8K) B[8K,16K); buf1: +16K

    // triangular tile map: blockIdx.x -> (bi, bj), bi <= bj
    int tt = blockIdx.x, bi = 0;
    while (tt >= NB - bi) { tt -= NB - bi; ++bi; }
    const int bj = bi + tt;
    const int i0 = bi * 128, j0 = bj * 128;
    const bool diag = (bi == bj);

    const int tid = threadIdx.x;
    const int w = tid >> 6, lane = tid & 63;
    const int quad = lane >> 4, lc = lane & 15;
    const int wy = w >> 1, wx = w & 1;

    // stage chunk cc into buffer bb (4 gload16 per thread, fixed order)
#define STAGE(cc, bb) do {                                                   \
        const int _dk = (cc) * 64;                                           \
        { const int _s = tid; const int _r = _s >> 2, _bo = (_s & 3) * 16;   \
          const int _lb = (bb) * 16384 + (w * 64) * 16;                      \
          gload16(q8 + (size_t)(i0 + _r) * D + _dk + _bo, smem + _lb);       \
          gload16(q8 + (size_t)(j0 + _r) * D + _dk + _bo, smem + 8192 + _lb); } \
        { const int _s = 256 + tid; const int _r = _s >> 2, _bo = (_s & 3) * 16; \
          const int _lb = (bb) * 16384 + (256 + w * 64) * 16;                \
          gload16(q8 + (size_t)(i0 + _r) * D + _dk + _bo, smem + _lb);       \
          gload16(q8 + (size_t)(j0 + _r) * D + _dk + _bo, smem + 8192 + _lb); } \
    } while (0)

    if (tid < 128) { sqI[tid] = sqv[i0 + tid]; tgI[tid] = tgt[i0 + tid]; }
    else { const int c = tid - 128; sqJ[c] = sqv[j0 + c]; tgJ[c] = tgt[j0 + c]; }

    // prologue prefetch: chunk 0 in flight while we init accumulators
    STAGE(0, 0);
    // sq/tg ds_writes visible to all waves; chunk-0 vmcnt stays outstanding
    asm volatile("s_waitcnt lgkmcnt(0)\n\ts_barrier" ::: "memory");

    // acc init: -(si + sqj)/2  =>  after MFMA chain, acc = -dist/2
    float sqjn[4];
    #pragma unroll
    for (int nt = 0; nt < 4; ++nt) sqjn[nt] = sqJ[wx * 64 + nt * 16 + lc];
    f32x4 acc[4][4];
    #pragma unroll
    for (int mt = 0; mt < 4; ++mt) {
        const f32x4 si4 = *(const f32x4*)&sqI[wy * 64 + mt * 16 + quad * 4];
        #pragma unroll
        for (int nt = 0; nt < 4; ++nt)
            #pragma unroll
            for (int r = 0; r < 4; ++r)
                acc[mt][nt][r] = -0.5f * (si4[r] + sqjn[nt]);
    }

    // K-loop: 4 chunks of K=64, 1-deep pipelined, counted vmcnt
    #pragma unroll
    for (int c = 0; c < 4; ++c) {
        if (c < 3) {
            STAGE(c + 1, (c + 1) & 1);
            // wait for chunk c's 4 loads only; c+1's 4 stay in flight
            asm volatile("s_waitcnt vmcnt(4)\n\ts_barrier" ::: "memory");
        } else {
            asm volatile("s_waitcnt vmcnt(0)\n\ts_barrier" ::: "memory");
        }
        const char* AP = smem + (c & 1) * 16384;
        const char* BP = AP + 8192;
        union { int4 v; i64 d[2]; } fb[4], fa;
        #pragma unroll
        for (int t = 0; t < 4; ++t)
            fb[t].v = *(const int4*)(BP + (wx * 64 + t * 16 + lc) * 64 + quad * 16);
        __builtin_amdgcn_s_setprio(1);
        #pragma unroll
        for (int mt = 0; mt < 4; ++mt) {
            fa.v = *(const int4*)(AP + (wy * 64 + mt * 16 + lc) * 64 + quad * 16);
            #pragma unroll
            for (int nt = 0; nt < 4; ++nt) {
                acc[mt][nt] = __builtin_amdgcn_mfma_f32_16x16x32_fp8_fp8(
                    fa.d[0], fb[nt].d[0], acc[mt][nt], 0, 0, 0);
                acc[mt][nt] = __builtin_amdgcn_mfma_f32_16x16x32_fp8_fp8(
                    fa.d[1], fb[nt].d[1], acc[mt][nt], 0, 0, 0);
            }
        }
        __builtin_amdgcn_s_setprio(0);
        // frag reads of buf[c&1] done before anyone stages chunk c+2 into it
        asm volatile("s_waitcnt lgkmcnt(0)\n\ts_barrier" ::: "memory");
    }
#undef STAGE
    // last trailing barrier above also makes staging LDS reusable as merge

    unsigned* const mpos = Msh;
    unsigned* const mneg = Msh + 128 * 33;

    // ---- epilogue: u32 keys, LDS-merge I-side, shuffle-merge J-side
    int tj[4]; unsigned jc[4], jpk[4], jnk[4];
    #pragma unroll
    for (int nt = 0; nt < 4; ++nt) {
        const int cl = wx * 64 + nt * 16 + lc;
        tj[nt] = tgJ[cl];
        jc[nt] = 0x1FFFu - (unsigned)(j0 + cl);   // I-side idx field (col)
    }

    if (!diag) {
        // masked-candidate inits: dominate every "losing-side" jc/rk candidate
        const unsigned rk0 = 0x1FFFu - (unsigned)i0;
        #pragma unroll
        for (int nt = 0; nt < 4; ++nt) { jpk[nt] = rk0; jnk[nt] = rk0; }

        #pragma unroll
        for (int mt = 0; mt < 4; ++mt) {
            const int rbase = wy * 64 + mt * 16 + quad * 4;
            const int4 ti4 = *(const int4*)&tgI[rbase];
            #pragma unroll
            for (int r = 0; r < 4; ++r) {
                const int sr = rbase + r;
                const unsigned rk = 0x1FFFu - (unsigned)(i0 + sr);  // J idx field
                const int ti = ((const int*)&ti4)[r];
                unsigned bpk = jc[0], bnk = jc[0];
                #pragma unroll
                for (int nt = 0; nt < 4; ++nt) {
                    const float dist = fmaxf(-2.0f * acc[mt][nt][r], 0.0f);
                    const unsigned db = __float_as_uint(dist) & 0xFFFFE000u;
                    const unsigned kI = db | jc[nt];
                    const unsigned kJ = db | rk;
                    const bool same = (ti == tj[nt]);
                    bpk = same ? max(bpk, kI) : bpk;
                    bnk = same ? bnk : max(bnk, kI);
                    jpk[nt] = same ? max(jpk[nt], kJ) : jpk[nt];
                    jnk[nt] = same ? jnk[nt] : max(jnk[nt], kJ);
                }
                mpos[sr * 33 + wx * 16 + lc] = bpk;
                mneg[sr * 33 + wx * 16 + lc] = bnk;
            }
        }
    } else {
        // diag tile: per-element self-exclusion; J-side never consumed
        #pragma unroll
        for (int mt = 0; mt < 4; ++mt) {
            const int rbase = wy * 64 + mt * 16 + quad * 4;
            const int4 ti4 = *(const int4*)&tgI[rbase];
            #pragma unroll
            for (int r = 0; r < 4; ++r) {
                const int sr = rbase + r;
                const int ti = ((const int*)&ti4)[r];
                unsigned bpk = 0u, bnk = 0u;
                #pragma unroll
                for (int nt = 0; nt < 4; ++nt) {
                    const int cl = wx * 64 + nt * 16 + lc;
                    const float dist = fmaxf(-2.0f * acc[mt][nt][r], 0.0f);
                    const unsigned db = __float_as_uint(dist) & 0xFFFFE000u;
                    const bool same = (ti == tj[nt]);
                    const bool dia = (sr == cl);
                    const unsigned pb_ = (same && !dia) ? db : 0u;
                    const unsigned nb_ = (!same && !dia) ? db : 0u;
                    bpk = max(bpk, dia ? 0u : (pb_ | jc[nt]));
                    bnk = max(bnk, dia ? 0u : (nb_ | jc[nt]));
                }
                mpos[sr * 33 + wx * 16 + lc] = bpk;
                mneg[sr * 33 + wx * 16 + lc] = bnk;
            }
        }
    }
    __syncthreads();

    // I-side owner merge: tid<128 -> pos row tid; tid>=128 -> neg row tid-128
    {
        const int sr = tid & 127;
        const unsigned* m = (tid < 128) ? &mpos[sr * 33] : &mneg[sr * 33];
        unsigned best = 0u;
        #pragma unroll
        for (int k = 0; k < 32; ++k) best = max(best, m[k]);
        unsigned* gk = (tid < 128) ? pos_key : neg_key;
        atomicMax(&gk[i0 + sr], best);
    }

    // J-side: merge 4 quads within wave, then atomic (both wy waves emit)
    if (!diag) {
        #pragma unroll
        for (int nt = 0; nt < 4; ++nt) {
            unsigned pk = jpk[nt], nk = jnk[nt];
            #pragma unroll
            for (int off = 16; off < 64; off <<= 1) {
                pk = max(pk, (unsigned)__shfl_xor((int)pk, off, 64));
                nk = max(nk, (unsigned)__shfl_xor((int)nk, off, 64));
            }
            if (quad == 0) {
                const int gcol = j0 + wx * 64 + nt * 16 + lc;
                atomicMax(&pos_key[gcol], pk);
                atomicMax(&neg_key[gcol], nk);
            }
        }
    }
}

// ---------------------------------------------------------------- kernel 2
// Fused finalize + mean.  512 blocks x 4 rows/wave (8 waves/CU).
// NEW: all key loads issued first, then all 12 gather float4 loads, then
// the reductions — one latency round instead of four serial chains.
__global__ __launch_bounds__(256) void final_kernel(
    const float* __restrict__ q, const unsigned* __restrict__ pos_key,
    const unsigned* __restrict__ neg_key, float* __restrict__ out)
{
    __shared__ float red[4];
    const int wv = threadIdx.x >> 6, lane = threadIdx.x & 63;
    const int rbase = (blockIdx.x * 4 + wv) * 4;

    int bpi[4], bni[4];
    #pragma unroll
    for (int rr = 0; rr < 4; ++rr) {
        bpi[rr] = 0x1FFF - (int)(pos_key[rbase + rr] & 0x1FFFu);
        bni[rr] = 0x1FFF - (int)(neg_key[rbase + rr] & 0x1FFFu);
    }
    float4 qi[4], qp[4], qn[4];
    #pragma unroll
    for (int rr = 0; rr < 4; ++rr) {
        qi[rr] = ((const float4*)(q + (size_t)(rbase + rr) * D))[lane];
        qp[rr] = ((const float4*)(q + (size_t)bpi[rr] * D))[lane];
        qn[rr] = ((const float4*)(q + (size_t)bni[rr] * D))[lane];
    }
    float wsum = 0.0f;
    #pragma unroll
    for (int rr = 0; rr < 4; ++rr) {
        float dx, dp = 0.0f, dn = 0.0f;
        dx = qi[rr].x - qp[rr].x; dp += dx * dx;
        dx = qi[rr].y - qp[rr].y; dp += dx * dx;
        dx = qi[rr].z - qp[rr].z; dp += dx * dx;
        dx = qi[rr].w - qp[rr].w; dp += dx * dx;
        dx = qi[rr].x - qn[rr].x; dn += dx * dx;
        dx = qi[rr].y - qn[rr].y; dn += dx * dx;
        dx = qi[rr].z - qn[rr].z; dn += dx * dx;
        dx = qi[rr].w - qn[rr].w; dn += dx * dx;
        #pragma unroll
        for (int off = 32; off; off >>= 1) {
            dp += __shfl_down(dp, off, 64);
            dn += __shfl_down(dn, off, 64);
        }
        if (lane == 0) wsum += fmaxf(0.0f, (1.0f - dp) + dn);
    }
    if (lane == 0) red[wv] = wsum;
    __syncthreads();
    if (threadIdx.x == 0)
        atomicAdd(out, (red[0] + red[1] + red[2] + red[3]) * (1.0f / N));
}

// ----------------------------------------------------------------
extern "C" void kernel_launch(void* const* d_in, const int* in_sizes, int n_in,
                              void* d_out, int out_size, void* d_ws, size_t ws_size,
                              hipStream_t stream) {
    const float* q = (const float*)d_in[0];
    const int* tgt = (const int*)d_in[1];
    float* out = (float*)d_out;

    // ws layout (~2.2 MB)
    unsigned* pos_key = (unsigned*)d_ws;              // N
    unsigned* neg_key = pos_key + N;                  // N
    unsigned char* q8 = (unsigned char*)(neg_key + N);// N*D bytes
    float* sqv = (float*)(q8 + (size_t)N * D);        // N

    prep_kernel<<<dim3(N / 4), dim3(256), 0, stream>>>(q, q8, sqv, pos_key, neg_key, out);
    mine_kernel<<<dim3(NTILES), dim3(256), 0, stream>>>(q8, tgt, sqv, pos_key, neg_key);
    final_kernel<<<dim3(512), dim3(256), 0, stream>>>(q, pos_key, neg_key, out);
}